// Round 2
// baseline (554.031 us; speedup 1.0000x reference)
//
#include <hip/hip_runtime.h>

#define NPTS 4096
#define BATCH 4
#define KNN 20
#define ROT 116
#define PTS 4
#define GITERS 8

__device__ __forceinline__ void vn_lrelu3(float p[3], const float d[3]) {
  float dot = p[0]*d[0] + p[1]*d[1] + p[2]*d[2];
  if (dot < 0.0f) {
    float dsq = d[0]*d[0] + d[1]*d[1] + d[2]*d[2];
    float r = dot / (dsq + 1e-6f);
    p[0] -= r*d[0]; p[1] -= r*d[1]; p[2] -= r*d[2];
  }
}

// ---------------- K1: KNN (top-20 smallest sq-dist per point) ----------------
// One wave per point. 64 candidates per lane, held in registers with static
// indexing only. 4 cached group-mins of 16; winner's lane recomputes its one
// group per pass using the lexicographic filter (d,j) > (win_d, win_j) --
// winners leave in strictly increasing (d,j) order, so the filter excludes
// exactly the removed elements and d[] is never modified.
#define RECOMP(G)                                                        \
  {                                                                      \
    float bdg = 3.4e38f; int bjg = 0x7fffffff;                           \
    _Pragma("unroll")                                                    \
    for (int s = 0; s < 16; ++s) {                                       \
      float ds = d[(G)*16 + s]; int js = j0 + (G)*16 + s;                \
      bool alive = (ds > rd) || (ds == rd && js > rj);                   \
      if (alive && (ds < bdg || (ds == bdg && js < bjg))) {              \
        bdg = ds; bjg = js;                                              \
      }                                                                  \
    }                                                                    \
    gd[G] = bdg; gj[G] = bjg;                                            \
  }

__global__ __launch_bounds__(256) void knn_kernel(const float* __restrict__ x,
                                                  int* __restrict__ knn) {
  const int wave = (blockIdx.x << 2) + (threadIdx.x >> 6);   // point row
  const int lane = threadIdx.x & 63;
  const int b = wave >> 12, i = wave & (NPTS - 1);
  const float* __restrict__ xb = x + b * 3 * NPTS;
  const float cx = xb[i], cy = xb[NPTS + i], cz = xb[2 * NPTS + i];
  const int j0 = lane << 6;                                  // lane owns [j0, j0+64)

  float d[64];
#pragma unroll
  for (int it = 0; it < 16; ++it) {
    const float4 px = *(const float4*)(xb + j0 + 4 * it);
    const float4 py = *(const float4*)(xb + NPTS + j0 + 4 * it);
    const float4 pz = *(const float4*)(xb + 2 * NPTS + j0 + 4 * it);
    float dx, dy, dz;
    dx = px.x - cx; dy = py.x - cy; dz = pz.x - cz; d[4*it+0] = dx*dx + dy*dy + dz*dz;
    dx = px.y - cx; dy = py.y - cy; dz = pz.y - cz; d[4*it+1] = dx*dx + dy*dy + dz*dz;
    dx = px.z - cx; dy = py.z - cy; dz = pz.z - cz; d[4*it+2] = dx*dx + dy*dy + dz*dz;
    dx = px.w - cx; dy = py.w - cy; dz = pz.w - cz; d[4*it+3] = dx*dx + dy*dy + dz*dz;
  }

  float gd[4]; int gj[4];
#pragma unroll
  for (int g = 0; g < 4; ++g) {
    float bdg = d[g * 16]; int bjg = j0 + g * 16;
#pragma unroll
    for (int s = 1; s < 16; ++s) {
      if (d[g * 16 + s] < bdg) { bdg = d[g * 16 + s]; bjg = j0 + g * 16 + s; }
    }
    gd[g] = bdg; gj[g] = bjg;
  }

  int* kp = knn + wave * KNN;
  for (int p = 0; p < KNN; ++p) {
    float bd = gd[0]; int bj = gj[0];
#pragma unroll
    for (int g = 1; g < 4; ++g)
      if (gd[g] < bd || (gd[g] == bd && gj[g] < bj)) { bd = gd[g]; bj = gj[g]; }
    float rd = bd; int rj = bj;
#pragma unroll
    for (int off = 32; off > 0; off >>= 1) {
      float od = __shfl_xor(rd, off);
      int   oj = __shfl_xor(rj, off);
      if (od < rd || (od == rd && oj < rj)) { rd = od; rj = oj; }
    }
    if (lane == 0) kp[p] = rj;
    const int rl = rj - j0;
    if (rl >= 0 && rl < 64) {          // exactly one lane owns the winner
      const int g = rl >> 4;
      if      (g == 0) RECOMP(0)
      else if (g == 1) RECOMP(1)
      else if (g == 2) RECOMP(2)
      else             RECOMP(3)
    }
  }
}

// ------- K2: edge features + first VNT layer + mean over k -> h[p][64][3] -------
__global__ __launch_bounds__(64) void edge_kernel(const float* __restrict__ x,
                                                  const int* __restrict__ knn,
                                                  const float* __restrict__ Wf,
                                                  const float* __restrict__ Wd,
                                                  float* __restrict__ h) {
  const int p = blockIdx.x;
  const int b = p >> 12, i = p & (NPTS - 1);
  const float* xb = x + b * 3 * NPTS;
  const float cx = xb[i], cy = xb[NPTS + i], cz = xb[2 * NPTS + i];
  __shared__ float e[KNN][3][3];   // [k][feat(diff,ctr,cross)][vec]
  const int t = threadIdx.x;
  if (t < KNN) {
    int j = knn[p * KNN + t];
    float nx = xb[j], ny = xb[NPTS + j], nz = xb[2 * NPTS + j];
    e[t][0][0] = nx - cx; e[t][0][1] = ny - cy; e[t][0][2] = nz - cz;
    e[t][1][0] = cx;      e[t][1][1] = cy;      e[t][1][2] = cz;
    e[t][2][0] = ny * cz - nz * cy;
    e[t][2][1] = nz * cx - nx * cz;
    e[t][2][2] = nx * cy - ny * cx;
  }
  __syncthreads();
  const int c = t;                               // 0..63 output channel
  float f0 = Wf[c * 3 + 0], f1 = Wf[c * 3 + 1], f2 = Wf[c * 3 + 2];
  float s = 1.0f / (f0 + f1 + f2);               // VNT row normalization
  f0 *= s; f1 *= s; f2 *= s;
  const float d0 = Wd[c * 3 + 0], d1 = Wd[c * 3 + 1], d2 = Wd[c * 3 + 2];
  float a0 = 0.f, a1 = 0.f, a2 = 0.f;
  for (int k = 0; k < KNN; ++k) {
    float pv[3], dv[3];
#pragma unroll
    for (int v = 0; v < 3; ++v) {
      pv[v] = f0 * e[k][0][v] + f1 * e[k][1][v] + f2 * e[k][2][v];
      dv[v] = d0 * e[k][0][v] + d1 * e[k][1][v] + d2 * e[k][2][v];
    }
    vn_lrelu3(pv, dv);
    a0 += pv[0]; a1 += pv[1]; a2 += pv[2];
  }
  const float inv = 1.0f / KNN;
  float* hp = h + p * 192 + c * 3;
  hp[0] = a0 * inv; hp[1] = a1 * inv; hp[2] = a2 * inv;
}

// ------- K3a: Wc1 -> Wc2 -> (hc = h - xc), Wt -> trans partials -------
__global__ __launch_bounds__(256) void center_kernel(
    const float* __restrict__ h,
    const float* __restrict__ Wc1f, const float* __restrict__ Wc1d,
    const float* __restrict__ Wc2f, const float* __restrict__ Wc2d,
    const float* __restrict__ Wtf,  const float* __restrict__ Wtd,
    float* __restrict__ hc, float* __restrict__ trans_part) {
  __shared__ float w1f[64][65], w1d[64][65], w2f[64][65], w2d[64][65];
  __shared__ float wtf[12][65], wtd[12][65];
  __shared__ float hin[PTS][64][3], tmp[PTS][64][3];
  __shared__ float tred[PTS][12][3];
  const int t = threadIdx.x;
  for (int e = t; e < 4096; e += 256) {
    int r = e >> 6, c = e & 63;
    w1f[r][c] = Wc1f[e]; w1d[r][c] = Wc1d[e];
    w2f[r][c] = Wc2f[e]; w2d[r][c] = Wc2d[e];
  }
  for (int e = t; e < 768; e += 256) {
    int r = e >> 6, c = e & 63;
    wtf[r][c] = Wtf[e]; wtd[r][c] = Wtd[e];
  }
  __syncthreads();
  if (t < 64) {                      // VNT row normalization
    float s = 0.f;
    for (int i = 0; i < 64; ++i) s += w1f[t][i];
    s = 1.0f / s;
    for (int i = 0; i < 64; ++i) w1f[t][i] *= s;
  } else if (t < 128) {
    int r = t - 64; float s = 0.f;
    for (int i = 0; i < 64; ++i) s += w2f[r][i];
    s = 1.0f / s;
    for (int i = 0; i < 64; ++i) w2f[r][i] *= s;
  } else if (t < 140) {
    int r = t - 128; float s = 0.f;
    for (int i = 0; i < 64; ++i) s += wtf[r][i];
    s = 1.0f / s;
    for (int i = 0; i < 64; ++i) wtf[r][i] *= s;
  }
  const int q = t >> 6, c = t & 63;
  const int blk = blockIdx.x;        // 0..511 (128 per batch)
  const int pbase = ((blk >> 7) << 12) + ((blk & 127) << 5);
  float tacc[3] = {0.f, 0.f, 0.f};
  for (int g = 0; g < GITERS; ++g) {
    __syncthreads();
    const int p0 = pbase + g * PTS;
    for (int e = t; e < PTS * 192; e += 256)
      ((float*)hin)[e] = h[p0 * 192 + e];
    __syncthreads();
    float pf[3] = {0,0,0}, pd[3] = {0,0,0};
    for (int i = 0; i < 64; ++i) {
      float wf = w1f[c][i], wd = w1d[c][i];
#pragma unroll
      for (int v = 0; v < 3; ++v) { pf[v] += wf * hin[q][i][v]; pd[v] += wd * hin[q][i][v]; }
    }
    vn_lrelu3(pf, pd);
#pragma unroll
    for (int v = 0; v < 3; ++v) tmp[q][c][v] = pf[v];
    __syncthreads();
    float qf[3] = {0,0,0}, qd[3] = {0,0,0};
    for (int i = 0; i < 64; ++i) {
      float wf = w2f[c][i], wd = w2d[c][i];
#pragma unroll
      for (int v = 0; v < 3; ++v) { qf[v] += wf * tmp[q][i][v]; qd[v] += wd * tmp[q][i][v]; }
    }
    vn_lrelu3(qf, qd);                 // qf = xc
    {
      float* hcp = hc + (p0 + q) * 192 + c * 3;
#pragma unroll
      for (int v = 0; v < 3; ++v) hcp[v] = hin[q][c][v] - qf[v];
    }
    __syncthreads();
#pragma unroll
    for (int v = 0; v < 3; ++v) tmp[q][c][v] = qf[v];   // xc into LDS
    __syncthreads();
    if (c < 12) {
      float tf[3] = {0,0,0}, td[3] = {0,0,0};
      for (int i = 0; i < 64; ++i) {
        float wf = wtf[c][i], wd = wtd[c][i];
#pragma unroll
        for (int v = 0; v < 3; ++v) { tf[v] += wf * tmp[q][i][v]; td[v] += wd * tmp[q][i][v]; }
      }
      vn_lrelu3(tf, td);
      tacc[0] += tf[0]; tacc[1] += tf[1]; tacc[2] += tf[2];
    }
  }
  __syncthreads();
  if (c < 12) {
#pragma unroll
    for (int v = 0; v < 3; ++v) tred[q][c][v] = tacc[v];
  }
  __syncthreads();
  if (t < 36) {
    int cc = t / 3, v = t % 3;
    trans_part[blk * 36 + t] =
        tred[0][cc][v] + tred[1][cc][v] + tred[2][cc][v] + tred[3][cc][v];
  }
}

// ------- K3b: W1 -> W2 -> W3 -> rot partials -------
__global__ __launch_bounds__(256) void rot_kernel(
    const float* __restrict__ hc,
    const float* __restrict__ W1f, const float* __restrict__ W1d,
    const float* __restrict__ W2f, const float* __restrict__ W2d,
    const float* __restrict__ W3,
    float* __restrict__ rot_part) {
  __shared__ float w1f[64][65], w1d[64][65], w2f[64][65], w2d[64][65];
  __shared__ float w3[ROT][65];
  __shared__ float hin[PTS][64][3], tmp[PTS][64][3];
  __shared__ float rred[PTS][ROT][3];
  const int t = threadIdx.x;
  for (int e = t; e < 4096; e += 256) {
    int r = e >> 6, c = e & 63;
    w1f[r][c] = W1f[e]; w1d[r][c] = W1d[e];
    w2f[r][c] = W2f[e]; w2d[r][c] = W2d[e];
  }
  for (int e = t; e < ROT * 64; e += 256)
    w3[e >> 6][e & 63] = W3[e];
  const int q = t >> 6, c = t & 63;
  const int blk = blockIdx.x;
  const int pbase = ((blk >> 7) << 12) + ((blk & 127) << 5);
  float r0[3] = {0,0,0}, r1[3] = {0,0,0};
  for (int g = 0; g < GITERS; ++g) {
    __syncthreads();
    const int p0 = pbase + g * PTS;
    for (int e = t; e < PTS * 192; e += 256)
      ((float*)hin)[e] = hc[p0 * 192 + e];
    __syncthreads();
    float pf[3] = {0,0,0}, pd[3] = {0,0,0};
    for (int i = 0; i < 64; ++i) {
      float wf = w1f[c][i], wd = w1d[c][i];
#pragma unroll
      for (int v = 0; v < 3; ++v) { pf[v] += wf * hin[q][i][v]; pd[v] += wd * hin[q][i][v]; }
    }
    vn_lrelu3(pf, pd);
#pragma unroll
    for (int v = 0; v < 3; ++v) tmp[q][c][v] = pf[v];
    __syncthreads();
    float qf[3] = {0,0,0}, qd[3] = {0,0,0};
    for (int i = 0; i < 64; ++i) {
      float wf = w2f[c][i], wd = w2d[c][i];
#pragma unroll
      for (int v = 0; v < 3; ++v) { qf[v] += wf * tmp[q][i][v]; qd[v] += wd * tmp[q][i][v]; }
    }
    vn_lrelu3(qf, qd);                 // qf = conv2 output
    __syncthreads();
#pragma unroll
    for (int v = 0; v < 3; ++v) hin[q][c][v] = qf[v];   // reuse hin for h2
    __syncthreads();
    float s0[3] = {0,0,0}, s1[3] = {0,0,0};
    for (int i = 0; i < 64; ++i) {
      float h0 = hin[q][i][0], h1 = hin[q][i][1], h2 = hin[q][i][2];
      float wa = w3[c][i];
      s0[0] += wa * h0; s0[1] += wa * h1; s0[2] += wa * h2;
      if (c + 64 < ROT) {
        float wb = w3[c + 64][i];
        s1[0] += wb * h0; s1[1] += wb * h1; s1[2] += wb * h2;
      }
    }
#pragma unroll
    for (int v = 0; v < 3; ++v) { r0[v] += s0[v]; r1[v] += s1[v]; }
  }
  __syncthreads();
#pragma unroll
  for (int v = 0; v < 3; ++v) rred[q][c][v] = r0[v];
  if (c + 64 < ROT) {
#pragma unroll
    for (int v = 0; v < 3; ++v) rred[q][c + 64][v] = r1[v];
  }
  __syncthreads();
  for (int e = t; e < ROT * 3; e += 256) {
    int cc = e / 3, v = e % 3;
    rot_part[blk * 348 + e] =
        rred[0][cc][v] + rred[1][cc][v] + rred[2][cc][v] + rred[3][cc][v];
  }
}

// ------- K4: reduce partials, /N, concat [rot(116), trans(12)] -------
__global__ __launch_bounds__(256) void finalize_kernel(const float* __restrict__ rot_part,
                                                       const float* __restrict__ trans_part,
                                                       float* __restrict__ out) {
  int o = blockIdx.x * 256 + threadIdx.x;
  if (o >= BATCH * 128 * 3) return;
  int b = o / 384, r = o % 384;
  int ch = r / 3, v = r % 3;
  float s = 0.f;
  if (ch < ROT) {
    for (int blk = b * 128; blk < b * 128 + 128; ++blk)
      s += rot_part[blk * 348 + ch * 3 + v];
  } else {
    int c2 = ch - ROT;
    for (int blk = b * 128; blk < b * 128 + 128; ++blk)
      s += trans_part[blk * 36 + c2 * 3 + v];
  }
  out[o] = s * (1.0f / NPTS);
}

extern "C" void kernel_launch(void* const* d_in, const int* in_sizes, int n_in,
                              void* d_out, int out_size, void* d_ws, size_t ws_size,
                              hipStream_t stream) {
  (void)in_sizes; (void)n_in; (void)out_size; (void)ws_size;
  const float* x     = (const float*)d_in[0];
  const float* Wposf = (const float*)d_in[1];
  const float* Wposd = (const float*)d_in[2];
  const float* Wc1f  = (const float*)d_in[3];
  const float* Wc1d  = (const float*)d_in[4];
  const float* Wc2f  = (const float*)d_in[5];
  const float* Wc2d  = (const float*)d_in[6];
  const float* Wtf   = (const float*)d_in[7];
  const float* Wtd   = (const float*)d_in[8];
  const float* W1f   = (const float*)d_in[9];
  const float* W1d   = (const float*)d_in[10];
  const float* W2f   = (const float*)d_in[11];
  const float* W2d   = (const float*)d_in[12];
  const float* W3    = (const float*)d_in[13];
  float* out = (float*)d_out;

  char* ws = (char*)d_ws;
  int*   knn        = (int*)ws;                                     // 16384*20*4   = 1,310,720 B
  float* h          = (float*)(ws + 1310720);                       // 16384*192*4  = 12,582,912 B
  float* hcbuf      = (float*)(ws + 1310720 + 12582912);            // 12,582,912 B
  float* trans_part = (float*)(ws + 1310720 + 2 * 12582912);        // 512*36*4     = 73,728 B
  float* rot_part   = (float*)(ws + 1310720 + 2 * 12582912 + 73728);// 512*348*4    = 712,704 B

  knn_kernel<<<BATCH * NPTS / 4, 256, 0, stream>>>(x, knn);
  edge_kernel<<<BATCH * NPTS, 64, 0, stream>>>(x, knn, Wposf, Wposd, h);
  center_kernel<<<512, 256, 0, stream>>>(h, Wc1f, Wc1d, Wc2f, Wc2d, Wtf, Wtd,
                                         hcbuf, trans_part);
  rot_kernel<<<512, 256, 0, stream>>>(hcbuf, W1f, W1d, W2f, W2d, W3, rot_part);
  finalize_kernel<<<6, 256, 0, stream>>>(rot_part, trans_part, out);
}

// Round 4
// 304.775 us; speedup vs baseline: 1.8178x; 1.8178x over previous
//
#include <hip/hip_runtime.h>

#define NPTS 4096
#define BATCH 4
#define KNN 20
#define ROT 116
#define PTS 4
#define GITERS 8

__device__ __forceinline__ void vn_lrelu3(float p[3], const float d[3]) {
  float dot = p[0]*d[0] + p[1]*d[1] + p[2]*d[2];
  if (dot < 0.0f) {
    float dsq = d[0]*d[0] + d[1]*d[1] + d[2]*d[2];
    float r = dot / (dsq + 1e-6f);
    p[0] -= r*d[0]; p[1] -= r*d[1]; p[2] -= r*d[2];
  }
}

// ---------------- K1: KNN via histogram select ----------------
// One 256-thread block per point. Each thread owns 16 candidates (register-
// resident uint distance bits). Histogram on dbits>>20 (monotone for d>=0),
// block scan finds the bin containing the 20th smallest, compaction of all
// candidates with bin <= B, then exact (dbits,j)-lex ranking over the short
// list writes winners directly in lax.top_k order.
__global__ __launch_bounds__(256) void knn_kernel(const float* __restrict__ x,
                                                  int* __restrict__ knn) {
  const int row = blockIdx.x;
  const int b = row >> 12, i = row & (NPTS - 1);
  const float* __restrict__ xb = x + b * 3 * NPTS;
  const float cx = xb[i], cy = xb[NPTS + i], cz = xb[2 * NPTS + i];
  const int t = threadIdx.x;
  const int j0 = t << 4;

  __shared__ unsigned int hist[2048];
  __shared__ unsigned int ld_[384];
  __shared__ int lj_[384];
  __shared__ unsigned int lcount;
  __shared__ int s_B;
  __shared__ int wtot[4];

  for (int k = t; k < 2048; k += 256) hist[k] = 0u;
  if (t == 0) lcount = 0u;
  __syncthreads();

  unsigned int db[16];
#pragma unroll
  for (int q = 0; q < 4; ++q) {
    const float4 px = *(const float4*)(xb + j0 + 4 * q);
    const float4 py = *(const float4*)(xb + NPTS + j0 + 4 * q);
    const float4 pz = *(const float4*)(xb + 2 * NPTS + j0 + 4 * q);
    float dx, dy, dz, dd;
    dx = px.x - cx; dy = py.x - cy; dz = pz.x - cz;
    dd = dx*dx + dy*dy + dz*dz; db[4*q+0] = __float_as_uint(dd);
    dx = px.y - cx; dy = py.y - cy; dz = pz.y - cz;
    dd = dx*dx + dy*dy + dz*dz; db[4*q+1] = __float_as_uint(dd);
    dx = px.z - cx; dy = py.z - cy; dz = pz.z - cz;
    dd = dx*dx + dy*dy + dz*dz; db[4*q+2] = __float_as_uint(dd);
    dx = px.w - cx; dy = py.w - cy; dz = pz.w - cz;
    dd = dx*dx + dy*dy + dz*dz; db[4*q+3] = __float_as_uint(dd);
  }
#pragma unroll
  for (int s = 0; s < 16; ++s) atomicAdd(&hist[db[s] >> 20], 1u);
  __syncthreads();

  // per-thread partial over 8 bins, then block-wide inclusive scan
  int v = 0;
#pragma unroll
  for (int s = 0; s < 8; ++s) v += (int)hist[t * 8 + s];
  const int myps = v;
  const int lane = t & 63;
#pragma unroll
  for (int off = 1; off < 64; off <<= 1) {
    int n = __shfl_up(v, off);
    if (lane >= off) v += n;
  }
  if (lane == 63) wtot[t >> 6] = v;
  __syncthreads();
  int woff = 0;
#pragma unroll
  for (int w = 0; w < 4; ++w) if (w < (t >> 6)) woff += wtot[w];
  const int cum_in = v + woff;
  const int cum_ex = cum_in - myps;
  if (cum_ex < KNN && cum_in >= KNN) {     // exactly one thread
    int cum = cum_ex, B = t * 8;
    for (int s = 0; s < 8; ++s) {
      const int hh = (int)hist[t * 8 + s];
      if (cum + hh >= KNN) { B = t * 8 + s; break; }
      cum += hh;
    }
    s_B = B;
  }
  __syncthreads();
  const unsigned int Bb = (unsigned int)s_B;
#pragma unroll
  for (int s = 0; s < 16; ++s) {
    if ((db[s] >> 20) <= Bb) {
      unsigned int pos = atomicAdd(&lcount, 1u);
      if (pos < 384u) { ld_[pos] = db[s]; lj_[pos] = j0 + s; }
    }
  }
  __syncthreads();
  const int n = min((int)lcount, 384);
  for (int idx = t; idx < n; idx += 256) {
    const unsigned int kd = ld_[idx]; const int kj = lj_[idx];
    int rank = 0;
    for (int m = 0; m < n; ++m) {
      const unsigned int md = ld_[m];
      rank += (md < kd || (md == kd && lj_[m] < kj)) ? 1 : 0;
    }
    if (rank < KNN) knn[row * KNN + rank] = kj;
  }
}

// ------- K2: edge features + first VNT layer + mean over k (4 pts/block) -------
__global__ __launch_bounds__(256) void edge_kernel(const float* __restrict__ x,
                                                   const int* __restrict__ knn,
                                                   const float* __restrict__ Wf,
                                                   const float* __restrict__ Wd,
                                                   float* __restrict__ h) {
  const int g = threadIdx.x >> 6;
  const int lane = threadIdx.x & 63;
  const int p = (blockIdx.x << 2) + g;
  const int b = p >> 12, i = p & (NPTS - 1);
  const float* xb = x + b * 3 * NPTS;
  const float cx = xb[i], cy = xb[NPTS + i], cz = xb[2 * NPTS + i];
  __shared__ float e[4][KNN][3][3];   // [grp][k][feat(diff,ctr,cross)][vec]
  if (lane < KNN) {
    int j = knn[p * KNN + lane];
    float nx = xb[j], ny = xb[NPTS + j], nz = xb[2 * NPTS + j];
    e[g][lane][0][0] = nx - cx; e[g][lane][0][1] = ny - cy; e[g][lane][0][2] = nz - cz;
    e[g][lane][1][0] = cx;      e[g][lane][1][1] = cy;      e[g][lane][1][2] = cz;
    e[g][lane][2][0] = ny * cz - nz * cy;
    e[g][lane][2][1] = nz * cx - nx * cz;
    e[g][lane][2][2] = nx * cy - ny * cx;
  }
  __syncthreads();
  const int c = lane;                            // 0..63 output channel
  float f0 = Wf[c * 3 + 0], f1 = Wf[c * 3 + 1], f2 = Wf[c * 3 + 2];
  float s = 1.0f / (f0 + f1 + f2);               // VNT row normalization
  f0 *= s; f1 *= s; f2 *= s;
  const float d0 = Wd[c * 3 + 0], d1 = Wd[c * 3 + 1], d2 = Wd[c * 3 + 2];
  float a0 = 0.f, a1 = 0.f, a2 = 0.f;
  for (int k = 0; k < KNN; ++k) {
    float pv[3], dv[3];
#pragma unroll
    for (int v = 0; v < 3; ++v) {
      pv[v] = f0 * e[g][k][0][v] + f1 * e[g][k][1][v] + f2 * e[g][k][2][v];
      dv[v] = d0 * e[g][k][0][v] + d1 * e[g][k][1][v] + d2 * e[g][k][2][v];
    }
    vn_lrelu3(pv, dv);
    a0 += pv[0]; a1 += pv[1]; a2 += pv[2];
  }
  const float inv = 1.0f / KNN;
  float* hp = h + p * 192 + c * 3;
  hp[0] = a0 * inv; hp[1] = a1 * inv; hp[2] = a2 * inv;
}

// ------- K3a: Wc1 -> Wc2 -> (hc = h - xc), Wt -> trans partials -------
__global__ __launch_bounds__(256) void center_kernel(
    const float* __restrict__ h,
    const float* __restrict__ Wc1f, const float* __restrict__ Wc1d,
    const float* __restrict__ Wc2f, const float* __restrict__ Wc2d,
    const float* __restrict__ Wtf,  const float* __restrict__ Wtd,
    float* __restrict__ hc, float* __restrict__ trans_part) {
  __shared__ float w1f[64][65], w1d[64][65], w2f[64][65], w2d[64][65];
  __shared__ float wtf[12][65], wtd[12][65];
  __shared__ float hin[PTS][64][3], tmp[PTS][64][3];
  __shared__ float tred[PTS][12][3];
  const int t = threadIdx.x;
  for (int e = t; e < 4096; e += 256) {
    int r = e >> 6, c = e & 63;
    w1f[r][c] = Wc1f[e]; w1d[r][c] = Wc1d[e];
    w2f[r][c] = Wc2f[e]; w2d[r][c] = Wc2d[e];
  }
  for (int e = t; e < 768; e += 256) {
    int r = e >> 6, c = e & 63;
    wtf[r][c] = Wtf[e]; wtd[r][c] = Wtd[e];
  }
  __syncthreads();
  if (t < 64) {                      // VNT row normalization
    float s = 0.f;
    for (int i = 0; i < 64; ++i) s += w1f[t][i];
    s = 1.0f / s;
    for (int i = 0; i < 64; ++i) w1f[t][i] *= s;
  } else if (t < 128) {
    int r = t - 64; float s = 0.f;
    for (int i = 0; i < 64; ++i) s += w2f[r][i];
    s = 1.0f / s;
    for (int i = 0; i < 64; ++i) w2f[r][i] *= s;
  } else if (t < 140) {
    int r = t - 128; float s = 0.f;
    for (int i = 0; i < 64; ++i) s += wtf[r][i];
    s = 1.0f / s;
    for (int i = 0; i < 64; ++i) wtf[r][i] *= s;
  }
  const int q = t >> 6, c = t & 63;
  const int blk = blockIdx.x;        // 0..511 (128 per batch)
  const int pbase = ((blk >> 7) << 12) + ((blk & 127) << 5);
  float tacc[3] = {0.f, 0.f, 0.f};
  for (int g = 0; g < GITERS; ++g) {
    __syncthreads();
    const int p0 = pbase + g * PTS;
    for (int e = t; e < PTS * 192; e += 256)
      ((float*)hin)[e] = h[p0 * 192 + e];
    __syncthreads();
    float pf[3] = {0,0,0}, pd[3] = {0,0,0};
    for (int i = 0; i < 64; ++i) {
      float wf = w1f[c][i], wd = w1d[c][i];
#pragma unroll
      for (int v = 0; v < 3; ++v) { pf[v] += wf * hin[q][i][v]; pd[v] += wd * hin[q][i][v]; }
    }
    vn_lrelu3(pf, pd);
#pragma unroll
    for (int v = 0; v < 3; ++v) tmp[q][c][v] = pf[v];
    __syncthreads();
    float qf[3] = {0,0,0}, qd[3] = {0,0,0};
    for (int i = 0; i < 64; ++i) {
      float wf = w2f[c][i], wd = w2d[c][i];
#pragma unroll
      for (int v = 0; v < 3; ++v) { qf[v] += wf * tmp[q][i][v]; qd[v] += wd * tmp[q][i][v]; }
    }
    vn_lrelu3(qf, qd);                 // qf = xc
    {
      float* hcp = hc + (p0 + q) * 192 + c * 3;
#pragma unroll
      for (int v = 0; v < 3; ++v) hcp[v] = hin[q][c][v] - qf[v];
    }
    __syncthreads();
#pragma unroll
    for (int v = 0; v < 3; ++v) tmp[q][c][v] = qf[v];   // xc into LDS
    __syncthreads();
    if (c < 12) {
      float tf[3] = {0,0,0}, td[3] = {0,0,0};
      for (int i = 0; i < 64; ++i) {
        float wf = wtf[c][i], wd = wtd[c][i];
#pragma unroll
        for (int v = 0; v < 3; ++v) { tf[v] += wf * tmp[q][i][v]; td[v] += wd * tmp[q][i][v]; }
      }
      vn_lrelu3(tf, td);
      tacc[0] += tf[0]; tacc[1] += tf[1]; tacc[2] += tf[2];
    }
  }
  __syncthreads();
  if (c < 12) {
#pragma unroll
    for (int v = 0; v < 3; ++v) tred[q][c][v] = tacc[v];
  }
  __syncthreads();
  if (t < 36) {
    int cc = t / 3, v = t % 3;
    trans_part[blk * 36 + t] =
        tred[0][cc][v] + tred[1][cc][v] + tred[2][cc][v] + tred[3][cc][v];
  }
}

// ------- K3b: W1 -> W2 -> W3 -> rot partials -------
__global__ __launch_bounds__(256) void rot_kernel(
    const float* __restrict__ hc,
    const float* __restrict__ W1f, const float* __restrict__ W1d,
    const float* __restrict__ W2f, const float* __restrict__ W2d,
    const float* __restrict__ W3,
    float* __restrict__ rot_part) {
  __shared__ float w1f[64][65], w1d[64][65], w2f[64][65], w2d[64][65];
  __shared__ float w3[ROT][65];
  __shared__ float hin[PTS][64][3], tmp[PTS][64][3];
  __shared__ float rred[PTS][ROT][3];
  const int t = threadIdx.x;
  for (int e = t; e < 4096; e += 256) {
    int r = e >> 6, c = e & 63;
    w1f[r][c] = W1f[e]; w1d[r][c] = W1d[e];
    w2f[r][c] = W2f[e]; w2d[r][c] = W2d[e];
  }
  for (int e = t; e < ROT * 64; e += 256)
    w3[e >> 6][e & 63] = W3[e];
  const int q = t >> 6, c = t & 63;
  const int blk = blockIdx.x;
  const int pbase = ((blk >> 7) << 12) + ((blk & 127) << 5);
  float r0[3] = {0,0,0}, r1[3] = {0,0,0};
  for (int g = 0; g < GITERS; ++g) {
    __syncthreads();
    const int p0 = pbase + g * PTS;
    for (int e = t; e < PTS * 192; e += 256)
      ((float*)hin)[e] = hc[p0 * 192 + e];
    __syncthreads();
    float pf[3] = {0,0,0}, pd[3] = {0,0,0};
    for (int i = 0; i < 64; ++i) {
      float wf = w1f[c][i], wd = w1d[c][i];
#pragma unroll
      for (int v = 0; v < 3; ++v) { pf[v] += wf * hin[q][i][v]; pd[v] += wd * hin[q][i][v]; }
    }
    vn_lrelu3(pf, pd);
#pragma unroll
    for (int v = 0; v < 3; ++v) tmp[q][c][v] = pf[v];
    __syncthreads();
    float qf[3] = {0,0,0}, qd[3] = {0,0,0};
    for (int i = 0; i < 64; ++i) {
      float wf = w2f[c][i], wd = w2d[c][i];
#pragma unroll
      for (int v = 0; v < 3; ++v) { qf[v] += wf * tmp[q][i][v]; qd[v] += wd * tmp[q][i][v]; }
    }
    vn_lrelu3(qf, qd);                 // qf = conv2 output
    __syncthreads();
#pragma unroll
    for (int v = 0; v < 3; ++v) hin[q][c][v] = qf[v];   // reuse hin for h2
    __syncthreads();
    float s0[3] = {0,0,0}, s1[3] = {0,0,0};
    for (int i = 0; i < 64; ++i) {
      float h0 = hin[q][i][0], h1 = hin[q][i][1], h2 = hin[q][i][2];
      float wa = w3[c][i];
      s0[0] += wa * h0; s0[1] += wa * h1; s0[2] += wa * h2;
      if (c + 64 < ROT) {
        float wb = w3[c + 64][i];
        s1[0] += wb * h0; s1[1] += wb * h1; s1[2] += wb * h2;
      }
    }
#pragma unroll
    for (int v = 0; v < 3; ++v) { r0[v] += s0[v]; r1[v] += s1[v]; }
  }
  __syncthreads();
#pragma unroll
  for (int v = 0; v < 3; ++v) rred[q][c][v] = r0[v];
  if (c + 64 < ROT) {
#pragma unroll
    for (int v = 0; v < 3; ++v) rred[q][c + 64][v] = r1[v];
  }
  __syncthreads();
  for (int e = t; e < ROT * 3; e += 256) {
    int cc = e / 3, v = e % 3;
    rot_part[blk * 348 + e] =
        rred[0][cc][v] + rred[1][cc][v] + rred[2][cc][v] + rred[3][cc][v];
  }
}

// ------- K4: reduce partials, /N, concat [rot(116), trans(12)] -------
__global__ __launch_bounds__(256) void finalize_kernel(const float* __restrict__ rot_part,
                                                       const float* __restrict__ trans_part,
                                                       float* __restrict__ out) {
  int o = blockIdx.x * 256 + threadIdx.x;
  if (o >= BATCH * 128 * 3) return;
  int b = o / 384, r = o % 384;
  int ch = r / 3, v = r % 3;
  float s = 0.f;
  if (ch < ROT) {
    for (int blk = b * 128; blk < b * 128 + 128; ++blk)
      s += rot_part[blk * 348 + ch * 3 + v];
  } else {
    int c2 = ch - ROT;
    for (int blk = b * 128; blk < b * 128 + 128; ++blk)
      s += trans_part[blk * 36 + c2 * 3 + v];
  }
  out[o] = s * (1.0f / NPTS);
}

extern "C" void kernel_launch(void* const* d_in, const int* in_sizes, int n_in,
                              void* d_out, int out_size, void* d_ws, size_t ws_size,
                              hipStream_t stream) {
  (void)in_sizes; (void)n_in; (void)out_size; (void)ws_size;
  const float* x     = (const float*)d_in[0];
  const float* Wposf = (const float*)d_in[1];
  const float* Wposd = (const float*)d_in[2];
  const float* Wc1f  = (const float*)d_in[3];
  const float* Wc1d  = (const float*)d_in[4];
  const float* Wc2f  = (const float*)d_in[5];
  const float* Wc2d  = (const float*)d_in[6];
  const float* Wtf   = (const float*)d_in[7];
  const float* Wtd   = (const float*)d_in[8];
  const float* W1f   = (const float*)d_in[9];
  const float* W1d   = (const float*)d_in[10];
  const float* W2f   = (const float*)d_in[11];
  const float* W2d   = (const float*)d_in[12];
  const float* W3    = (const float*)d_in[13];
  float* out = (float*)d_out;

  char* ws = (char*)d_ws;
  int*   knn        = (int*)ws;                                     // 16384*20*4   = 1,310,720 B
  float* h          = (float*)(ws + 1310720);                       // 16384*192*4  = 12,582,912 B
  float* hcbuf      = (float*)(ws + 1310720 + 12582912);            // 12,582,912 B
  float* trans_part = (float*)(ws + 1310720 + 2 * 12582912);        // 512*36*4     = 73,728 B
  float* rot_part   = (float*)(ws + 1310720 + 2 * 12582912 + 73728);// 512*348*4    = 712,704 B

  knn_kernel<<<BATCH * NPTS, 256, 0, stream>>>(x, knn);
  edge_kernel<<<BATCH * NPTS / 4, 256, 0, stream>>>(x, knn, Wposf, Wposd, h);
  center_kernel<<<512, 256, 0, stream>>>(h, Wc1f, Wc1d, Wc2f, Wc2d, Wtf, Wtd,
                                         hcbuf, trans_part);
  rot_kernel<<<512, 256, 0, stream>>>(hcbuf, W1f, W1d, W2f, W2d, W3, rot_part);
  finalize_kernel<<<6, 256, 0, stream>>>(rot_part, trans_part, out);
}